// Round 1
// 1032.749 us; speedup vs baseline: 1.0824x; 1.0824x over previous
//
#include <hip/hip_runtime.h>
#include <hip/hip_bf16.h>
#include <cstdint>
#include <cstddef>

#define TOK  8192
#define DIN  1024
#define HID  2048
#define DOUTN 1024
#define NEXP 8
#define GHID 1024

typedef __attribute__((ext_vector_type(8))) short bf16x8;
typedef __attribute__((ext_vector_type(4))) float floatx4;
typedef __attribute__((ext_vector_type(8))) unsigned short ushort8v;

__device__ __forceinline__ unsigned short f2b(float f) {
  unsigned int u = __float_as_uint(f);
  u += 0x7fffu + ((u >> 16) & 1u);
  return (unsigned short)(u >> 16);
}

__device__ __forceinline__ float b2f(unsigned short b) {
  return __uint_as_float(((unsigned int)b) << 16);
}

__device__ __forceinline__ void async_cp16(const unsigned short* g, char* lds) {
  __builtin_amdgcn_global_load_lds(
      (const __attribute__((address_space(1))) unsigned int*)g,
      (__attribute__((address_space(3))) unsigned int*)lds, 16, 0, 0);
}

// ---------------- conversions ----------------

// x fp32 -> xb (bf16 hi) and xcat [TOK][3072] = [hi | hi | lo] (gating A operand)
__global__ void cvt_x_kernel(const float* __restrict__ src,
                             unsigned short* __restrict__ xb,
                             unsigned short* __restrict__ xcat, int n4) {
  int i = blockIdx.x * blockDim.x + threadIdx.x;
  if (i >= n4) return;
  float4 v = ((const float4*)src)[i];
  ushort4 hi, lo;
  hi.x = f2b(v.x); lo.x = f2b(v.x - b2f(hi.x));
  hi.y = f2b(v.y); lo.y = f2b(v.y - b2f(hi.y));
  hi.z = f2b(v.z); lo.z = f2b(v.z - b2f(hi.z));
  hi.w = f2b(v.w); lo.w = f2b(v.w - b2f(hi.w));
  ((ushort4*)xb)[i] = hi;
  int t = i >> 8;        // DIN/4 = 256 float4 per row
  int kk = i & 255;
  ushort4* rowc = (ushort4*)(xcat + (size_t)t * 3072);
  rowc[kk] = hi;
  rowc[256 + kk] = hi;
  rowc[512 + kk] = lo;
}

// src [E][K][N] fp32 -> dst [E][N][ldDst] bf16 (64x64 tiles, vectorized)
__global__ void cvt_transpose_v2(const float* __restrict__ src,
                                 unsigned short* __restrict__ dst, int N,
                                 long sEstride, long dEstride, int ldDst) {
  __shared__ __align__(16) unsigned short t[64][72];
  long e = blockIdx.z;
  src += e * sEstride;
  dst += e * dEstride;
  int n0 = blockIdx.x * 64, k0 = blockIdx.y * 64;
  int tid = threadIdx.x;
  int kr = tid >> 2, qc = tid & 3;
  const float* s = src + (long)(k0 + kr) * N + n0 + qc * 16;
#pragma unroll
  for (int i = 0; i < 4; i++) {
    float4 v = *(const float4*)(s + i * 4);
    int nn = qc * 16 + i * 4;
    t[nn + 0][kr] = f2b(v.x);
    t[nn + 1][kr] = f2b(v.y);
    t[nn + 2][kr] = f2b(v.z);
    t[nn + 3][kr] = f2b(v.w);
  }
  __syncthreads();
  int c = tid & 7;     // 16B chunk along k
  int nr = tid >> 3;   // 0..31
#pragma unroll
  for (int p = 0; p < 2; p++) {
    int n = nr + 32 * p;
    ushort8v v = *(const ushort8v*)&t[n][c * 8];
    *(ushort8v*)(dst + (long)(n0 + n) * ldDst + k0 + c * 8) = v;
  }
}

// gw1 [DIN][GHID] fp32 -> gw1t3 [GHID][3072] bf16 = [W_hi^T | W_lo^T | W_hi^T]
__global__ void cvt_gw1_kernel(const float* __restrict__ src,
                               unsigned short* __restrict__ dst) {
  __shared__ float tile[32][33];
  int n0 = blockIdx.x * 32, k0 = blockIdx.y * 32;
  int x = threadIdx.x, y = threadIdx.y;
#pragma unroll
  for (int i = 0; i < 4; i++)
    tile[y + 8 * i][x] = src[(long)(k0 + y + 8 * i) * GHID + n0 + x];
  __syncthreads();
#pragma unroll
  for (int i = 0; i < 4; i++) {
    float v = tile[x][y + 8 * i];
    unsigned short hi = f2b(v);
    unsigned short lo = f2b(v - b2f(hi));
    size_t r = (size_t)(n0 + y + 8 * i) * 3072 + k0 + x;
    dst[r] = hi;
    dst[r + 1024] = lo;
    dst[r + 2048] = hi;
  }
}

// ---------------- MFMA K-loop body (gating kernel, 128x128x32) ----------------

#define KLOOP(pa0, pa1, pb0, pb1, NKT)                                        \
  for (int kt = 0; kt < (NKT); ++kt) {                                        \
    __syncthreads();                                                          \
    async_cp16((pa0) + kt * 32, ldsA0);                                       \
    async_cp16((pa1) + kt * 32, ldsA0 + 4096);                                \
    async_cp16((pb0) + kt * 32, ldsB0);                                       \
    async_cp16((pb1) + kt * 32, ldsB0 + 4096);                                \
    __syncthreads();                                                          \
    bf16x8 af[4], bfr[4];                                                     \
    _Pragma("unroll") for (int i = 0; i < 4; i++) {                           \
      af[i] = *(const bf16x8*)(AsB + i * 1024);                               \
      bfr[i] = *(const bf16x8*)(BsB + i * 1024);                              \
    }                                                                         \
    _Pragma("unroll") for (int mi = 0; mi < 4; mi++)                          \
      _Pragma("unroll") for (int ni = 0; ni < 4; ni++)                        \
        acc[mi][ni] = __builtin_amdgcn_mfma_f32_16x16x32_bf16(                \
            af[mi], bfr[ni], acc[mi][ni], 0, 0, 0);                           \
  }

#define TILE_SETUP()                                                          \
  int tid = threadIdx.x;                                                      \
  int sr = tid >> 2;                                                          \
  int lchunk = (tid & 3) ^ ((sr >> 1) & 3);                                   \
  int koffA = lchunk * 8;                                                     \
  char* ldsA0 = (char*)As + (tid & 192) * 16;                                 \
  char* ldsB0 = (char*)Bs + (tid & 192) * 16;                                 \
  int lane = tid & 63, wv = tid >> 6;                                         \
  int wm = (wv >> 1) << 6, wn = (wv & 1) << 6;                                \
  int q = lane >> 4, l15 = lane & 15;                                         \
  int abase = l15 * 64 + ((q ^ ((l15 >> 1) & 3)) << 4);                       \
  const char* AsB = (const char*)As + wm * 64 + abase;                        \
  const char* BsB = (const char*)Bs + wn * 64 + abase;                        \
  floatx4 acc[4][4] = {};

// ---------------- gating layer-1: split-bf16 MFMA GEMM ----------------

__global__ __launch_bounds__(256, 4) void gating_mfma(
    const unsigned short* __restrict__ xcat,
    const unsigned short* __restrict__ gw1t3,
    const float* __restrict__ gb1, float* __restrict__ H) {
  __shared__ __align__(16) unsigned short As[128 * 32];
  __shared__ __align__(16) unsigned short Bs[128 * 32];
  TILE_SETUP();
  int row0 = blockIdx.y << 7, tn = blockIdx.x << 7;

  const unsigned short* a0p = xcat + (size_t)(row0 + sr) * 3072 + koffA;
  const unsigned short* a1p = xcat + (size_t)(row0 + 64 + sr) * 3072 + koffA;
  const unsigned short* b0p = gw1t3 + (size_t)(tn + sr) * 3072 + koffA;
  const unsigned short* b1p = gw1t3 + (size_t)(tn + 64 + sr) * 3072 + koffA;

  KLOOP(a0p, a1p, b0p, b1p, 3072 / 32);

  int crow = row0 + wm + q * 4;
  int ccol0 = tn + wn + l15;
#pragma unroll
  for (int ni = 0; ni < 4; ++ni) {
    int col = ccol0 + ni * 16;
    float bias = gb1[col];
#pragma unroll
    for (int mi = 0; mi < 4; ++mi)
#pragma unroll
      for (int rg = 0; rg < 4; ++rg) {
        int rr = crow + mi * 16 + rg;
        H[(size_t)rr * GHID + col] = fmaxf(acc[mi][ni][rg] + bias, 0.f);
      }
  }
}

// ---------------- gating: logits + top-2 + softmax ----------------

__global__ void gating2_topk(const float* __restrict__ H,
                             const float* __restrict__ gw2,
                             const float* __restrict__ gb2,
                             int* __restrict__ gidx, float* __restrict__ gwt) {
  int wv = threadIdx.x >> 6, lane = threadIdx.x & 63;
  int t = blockIdx.x * 4 + wv;
  const float* hrow = H + (size_t)t * GHID;
  float acc[8] = {};
  for (int k = lane; k < GHID; k += 64) {
    float v = hrow[k];
    float4 g0 = *(const float4*)(gw2 + (size_t)k * 8);
    float4 g1 = *(const float4*)(gw2 + (size_t)k * 8 + 4);
    acc[0] += v * g0.x; acc[1] += v * g0.y; acc[2] += v * g0.z; acc[3] += v * g0.w;
    acc[4] += v * g1.x; acc[5] += v * g1.y; acc[6] += v * g1.z; acc[7] += v * g1.w;
  }
#pragma unroll
  for (int off = 32; off > 0; off >>= 1)
#pragma unroll
    for (int e = 0; e < 8; e++) acc[e] += __shfl_xor(acc[e], off);

  if (lane == 0) {
    float l[8];
#pragma unroll
    for (int e = 0; e < 8; e++) l[e] = acc[e] + gb2[e];
    int b0 = 0; float v0 = l[0];
#pragma unroll
    for (int e = 1; e < 8; e++) if (l[e] > v0) { v0 = l[e]; b0 = e; }
    int b1 = -1; float v1 = -3.4e38f;
#pragma unroll
    for (int e = 0; e < 8; e++)
      if (e != b0 && l[e] > v1) { v1 = l[e]; b1 = e; }
    float ex = expf(v1 - v0);
    float inv = 1.f / (1.f + ex);
    gidx[2 * t] = b0; gidx[2 * t + 1] = b1;
    gwt[2 * t] = inv; gwt[2 * t + 1] = ex * inv;
  }
}

// ---------------- routing: count / scan / scatter ----------------

__global__ void route_count(const int* __restrict__ gidx, int* cnt) {
  int t = blockIdx.x * blockDim.x + threadIdx.x;
  int lane = threadIdx.x & 63;
  int e0 = gidx[2 * t], e1 = gidx[2 * t + 1];
#pragma unroll 1
  for (int e = 0; e < NEXP; e++) {
    unsigned long long m0 = __ballot(e0 == e);
    if (m0 && lane == __ffsll(m0) - 1) atomicAdd(&cnt[e], (int)__popcll(m0));
    unsigned long long m1 = __ballot(e1 == e);
    if (m1 && lane == __ffsll(m1) - 1) atomicAdd(&cnt[e], (int)__popcll(m1));
  }
}

__global__ void route_scan(const int* __restrict__ cnt, int* base_, int* cur) {
  if (threadIdx.x == 0) {
    int s = 0;
    for (int e = 0; e < NEXP; e++) { base_[e] = s; cur[e] = s; s += cnt[e]; }
  }
}

__global__ void route_scatter(const int* __restrict__ gidx,
                              const float* __restrict__ gwt, int* cur,
                              int* __restrict__ rt, float* __restrict__ rw,
                              int* __restrict__ inv) {
  int t = blockIdx.x * blockDim.x + threadIdx.x;
  int lane = threadIdx.x & 63;
  int e0 = gidx[2 * t], e1 = gidx[2 * t + 1];
  float w0 = gwt[2 * t], w1 = gwt[2 * t + 1];
#pragma unroll 1
  for (int e = 0; e < NEXP; e++) {
#pragma unroll 1
    for (int s = 0; s < 2; s++) {
      int mye = s ? e1 : e0;
      unsigned long long m = __ballot(mye == e);
      if (m) {
        int leader = __ffsll(m) - 1;
        int bb = 0;
        if (lane == leader) bb = atomicAdd(&cur[e], (int)__popcll(m));
        bb = __shfl(bb, leader);
        if (mye == e) {
          int pos = bb + (int)__popcll(m & ((1ull << lane) - 1ull));
          rt[pos] = t;
          rw[pos] = s ? w1 : w0;
          inv[2 * t + s] = pos;
        }
      }
    }
  }
}

// gather x rows into hx[slot][2048..3071]
__global__ void xgather_kernel(const unsigned short* __restrict__ xb,
                               const int* __restrict__ rt,
                               unsigned short* __restrict__ hx) {
  int slot = blockIdx.x;
  int c = threadIdx.x;  // 128 threads x ushort8 = 1024 elems
  int t = rt[slot];
  ((ushort8v*)(hx + (size_t)slot * 3072 + 2048))[c] =
      ((const ushort8v*)(xb + (size_t)t * 1024))[c];
}

// out[t] = s3[inv[2t]] + s3[inv[2t+1]]
__global__ void combine_kernel(const float* __restrict__ s3,
                               const int* __restrict__ inv,
                               float* __restrict__ out) {
  int t = blockIdx.x;
  int c = threadIdx.x;  // 256 threads x float4 = 1024
  const float4* r0 = (const float4*)(s3 + (size_t)inv[2 * t] * DOUTN);
  const float4* r1 = (const float4*)(s3 + (size_t)inv[2 * t + 1] * DOUTN);
  float4 a = r0[c], b = r1[c];
  float4 o = {a.x + b.x, a.y + b.y, a.z + b.z, a.w + b.w};
  ((float4*)(out + (size_t)t * DOUTN))[c] = o;
}

// ---------------- expert GEMMs: 256x256xBK64, 8-phase counted-vmcnt ----------
// Port of the m201 8-phase template (cdna_hip_programming.md §5) to grouped
// experts. 512 threads = 8 waves (2M x 4N); per-wave C = 128x64.
// LDS 128 KiB: A,B tiles [256 rows][64 k] bf16, double buffered.
// LDS rows are 128 B; chunk swizzle: LDS[row][slot] holds global k-chunk
// slot^(row&7). Write side = pre-swizzled GLOBAL source + linear
// global_load_lds dest (rule #21); read side slot = ((kk<<2)|q)^(l15&7).
// -> worst 2 lanes/bank on ds_read_b128 (free, m136).
// Stage units = 8 KB (64 rows) x 8 per K-tile; schedule (per K-tile t):
//   P0: read A(h0)+B(c0), stage B[2],B[3](t+1) -> other buf, MFMA q(0,0)
//   P1: read B(c1),       stage A[0],A[2](t+2) -> this buf,  MFMA q(0,1)
//   P2: read A(h1),       stage B[0],B[1](t+2) -> this buf,  MFMA q(1,1)
//   P3: (regs only)       stage A[1],A[3](t+2) -> this buf,  MFMA q(1,0)
//   then s_waitcnt vmcnt(6)  (3 units of t+2 stay in flight), s_barrier.
// Every stage unit is written one barrier-separated phase after its last
// ds_read; vmcnt ledger: 14 in flight at P3 -> drain 8 = tile t+1 complete.

#define STG_AU(dst, u, ktI)                                                   \
  async_cp16(Abase + aOff[u] + (size_t)(ktI) * 64, (dst) + (u) * 8192 + wvb)
#define STG_BU(dst, u, ktI)                                                   \
  async_cp16(Bbase + bOff[u] + (size_t)(ktI) * 64, (dst) + (u) * 8192 + wvb)

#define LDA8(dst, baseA, h)                                                   \
  _Pragma("unroll") for (int mi = 0; mi < 4; ++mi)                            \
      _Pragma("unroll") for (int kk = 0; kk < 2; ++kk)                        \
          (dst)[mi * 2 + kk] = *(const bf16x8*)(                              \
              (baseA) + ((wmo + (h)*64 + mi * 16 + l15) * 128 +               \
                         ((s0 ^ (kk << 2)) * 16)));

#define LDB4(dst, baseB, ch)                                                  \
  _Pragma("unroll") for (int ni = 0; ni < 2; ++ni)                            \
      _Pragma("unroll") for (int kk = 0; kk < 2; ++kk)                        \
          (dst)[ni * 2 + kk] = *(const bf16x8*)(                              \
              (baseB) + ((wno + (ch)*32 + ni * 16 + l15) * 128 +              \
                         ((s0 ^ (kk << 2)) * 16)));

#define MM8(aF, bF, mo, no)                                                   \
  _Pragma("unroll") for (int mi = 0; mi < 4; ++mi)                            \
      _Pragma("unroll") for (int ni = 0; ni < 2; ++ni)                        \
          _Pragma("unroll") for (int kk = 0; kk < 2; ++kk)                    \
              acc[(mo) + mi][(no) + ni] =                                     \
                  __builtin_amdgcn_mfma_f32_16x16x32_bf16(                    \
                      (aF)[mi * 2 + kk], (bF)[ni * 2 + kk],                   \
                      acc[(mo) + mi][(no) + ni], 0, 0, 0);

// MODE 1: hx[:,0:2048]  = relu(hx[:,2048:] @ w1 + b1)     K=1024
// MODE 2: obuf          = relu(hx @ [w2;wp] + b2 + bp)    K=3072
// MODE 3: s3            = (obuf @ w3 + b3) * gatew        K=2048

template <int MODE>
__global__ __launch_bounds__(512, 2) void moe_gemm8(
    const unsigned short* __restrict__ hx, const unsigned short* __restrict__ obuf,
    const unsigned short* __restrict__ w1t, const unsigned short* __restrict__ w2p,
    const unsigned short* __restrict__ w3t, const float* __restrict__ b1,
    const float* __restrict__ b2, const float* __restrict__ bp,
    const float* __restrict__ b3, const float* __restrict__ rw,
    const int* __restrict__ cnt, const int* __restrict__ basep,
    unsigned short* __restrict__ hxout, unsigned short* __restrict__ oout,
    float* __restrict__ s3) {
  __shared__ __align__(16) char smem[131072];

  // T1: XCD-aware bijective block swizzle (m204 form; nwg % 8 != 0 here)
  const int gx = (int)gridDim.x;
  const int nwg = gx * (int)gridDim.y;
  int orig = (int)blockIdx.y * gx + (int)blockIdx.x;
  int q8 = nwg >> 3, r8 = nwg & 7;
  int xcd = orig & 7, loc = orig >> 3;
  int wg = (xcd < r8 ? xcd * (q8 + 1) : r8 * (q8 + 1) + (xcd - r8) * q8) + loc;
  int bx = wg % gx, by = wg / gx;

  // expert / row-tile lookup
  int lt = by;
  int e, cn = 0, ok = 0;
  for (e = 0; e < NEXP; ++e) {
    int c = cnt[e];
    int nt = (c + 255) >> 8;
    if (lt < nt) { cn = c; ok = 1; break; }
    lt -= nt;
  }
  if (!ok) return;
  const int be = basep[e];
  const int row0 = lt << 8;
  const int tn = bx << 8;
  const int cnm1 = cn - 1;

  const int tid = threadIdx.x;
  const int lane = tid & 63, wv = tid >> 6;
  const int wmo = (wv >> 2) * 128;  // wave M offset: 0 / 128
  const int wno = (wv & 3) * 64;    // wave N offset: 0 / 64 / 128 / 192
  const int q = lane >> 4, l15 = lane & 15;
  const int s0 = q ^ (l15 & 7);     // read-side swizzle slot (kk=0)
  const int wvb = wv * 1024;
  const int srow = tid >> 3;                       // 0..63
  const int skoff = ((tid & 7) ^ (srow & 7)) * 8;  // pre-swizzled src k chunk

  const unsigned short* Abase;
  const unsigned short* Bbase;
  size_t strideA, strideB;
  if (MODE == 1) {
    Abase = hx + 2048; strideA = 3072;
    Bbase = w1t + (size_t)e * HID * DIN; strideB = DIN;
  } else if (MODE == 2) {
    Abase = hx; strideA = 3072;
    Bbase = w2p + (size_t)e * HID * 3072; strideB = 3072;
  } else {
    Abase = obuf; strideA = HID;
    Bbase = w3t + (size_t)e * DOUTN * HID; strideB = HID;
  }
  const int NT = (MODE == 1) ? (DIN / 64) : (MODE == 2 ? (3072 / 64) : (HID / 64));

  // per-thread staging source offsets (elements), rows clamped per thread
  size_t aOff[4], bOff[4];
#pragma unroll
  for (int u = 0; u < 4; ++u) {
    int ra = min(row0 + u * 64 + srow, cnm1);
    aOff[u] = (size_t)(be + ra) * strideA + skoff;
    bOff[u] = (size_t)(tn + u * 64 + srow) * strideB + skoff;
  }

  char* const A0s = smem;           // buf0 A [256][64] bf16
  char* const B0s = smem + 32768;   // buf0 B
  char* const A1s = smem + 65536;   // buf1 A
  char* const B1s = smem + 98304;   // buf1 B

  floatx4 acc[8][4] = {};
  bf16x8 a[8], bA[4], bB[4];

  // ---- prologue: tile0 fully, then 6/8 units of tile1 ----
  STG_AU(A0s, 0, 0); STG_AU(A0s, 1, 0); STG_AU(A0s, 2, 0); STG_AU(A0s, 3, 0);
  STG_BU(B0s, 0, 0); STG_BU(B0s, 1, 0); STG_BU(B0s, 2, 0); STG_BU(B0s, 3, 0);
  asm volatile("s_waitcnt vmcnt(4)" ::: "memory");
  STG_AU(A1s, 0, 1); STG_AU(A1s, 2, 1);
  STG_BU(B1s, 0, 1); STG_BU(B1s, 1, 1);
  STG_AU(A1s, 1, 1); STG_AU(A1s, 3, 1);
  asm volatile("s_waitcnt vmcnt(6)" ::: "memory");
  __builtin_amdgcn_s_barrier();

  for (int t = 0; t < NT; ++t) {
    char* const curA = (t & 1) ? A1s : A0s;
    char* const curB = (t & 1) ? B1s : B0s;
    char* const nxtB = (t & 1) ? B0s : B1s;
    // ---- P0 ----
    LDA8(a, curA, 0);
    LDB4(bA, curB, 0);
    if (t + 1 < NT) { STG_BU(nxtB, 2, t + 1); STG_BU(nxtB, 3, t + 1); }
    __builtin_amdgcn_s_barrier();
    asm volatile("s_waitcnt lgkmcnt(0)" ::: "memory");
    __builtin_amdgcn_s_setprio(1);
    MM8(a, bA, 0, 0);
    __builtin_amdgcn_s_setprio(0);
    __builtin_amdgcn_s_barrier();
    // ---- P1 ----
    LDB4(bB, curB, 1);
    if (t + 2 < NT) { STG_AU(curA, 0, t + 2); STG_AU(curA, 2, t + 2); }
    __builtin_amdgcn_s_barrier();
    asm volatile("s_waitcnt lgkmcnt(0)" ::: "memory");
    __builtin_amdgcn_s_setprio(1);
    MM8(a, bB, 0, 2);
    __builtin_amdgcn_s_setprio(0);
    __builtin_amdgcn_s_barrier();
    // ---- P2 ----
    LDA8(a, curA, 1);
    if (t + 2 < NT) { STG_BU(curB, 0, t + 2); STG_BU(curB, 1, t + 2); }
    __builtin_amdgcn_s_barrier();
    asm volatile("s_waitcnt lgkmcnt(0)" ::: "memory");
    __builtin_amdgcn_s_setprio(1);
    MM8(a, bB, 4, 2);
    __builtin_amdgcn_s_setprio(0);
    __builtin_amdgcn_s_barrier();
    // ---- P3 (regs only; counted vmcnt, never 0 mid-loop) ----
    if (t + 2 < NT) {
      STG_AU(curA, 1, t + 2); STG_AU(curA, 3, t + 2);
      __builtin_amdgcn_s_setprio(1);
      MM8(a, bA, 4, 0);
      __builtin_amdgcn_s_setprio(0);
      asm volatile("s_waitcnt vmcnt(6)" ::: "memory");
    } else {
      __builtin_amdgcn_s_setprio(1);
      MM8(a, bA, 4, 0);
      __builtin_amdgcn_s_setprio(0);
      asm volatile("s_waitcnt vmcnt(0)" ::: "memory");
    }
    __builtin_amdgcn_s_barrier();
  }

  // ---- epilogue (C/D: col=lane&15, row=(lane>>4)*4+reg; frag offsets 16*idx)
  const int crow = row0 + wmo + q * 4;
  const int ccol0 = tn + wno + l15;
  if (MODE == 1) {
    const float* bb = b1 + (size_t)e * HID;
    float bias[4];
#pragma unroll
    for (int ni = 0; ni < 4; ++ni) bias[ni] = bb[ccol0 + ni * 16];
#pragma unroll
    for (int mi = 0; mi < 8; ++mi)
#pragma unroll
      for (int rg = 0; rg < 4; ++rg) {
        int rr = crow + mi * 16 + rg;
        if (rr < cn) {
#pragma unroll
          for (int ni = 0; ni < 4; ++ni)
            hxout[(size_t)(be + rr) * 3072 + ccol0 + ni * 16] =
                f2b(fmaxf(acc[mi][ni][rg] + bias[ni], 0.f));
        }
      }
  } else if (MODE == 2) {
    const float* bb = b2 + (size_t)e * HID;
    const float* bq = bp + (size_t)e * HID;
    float bias[4];
#pragma unroll
    for (int ni = 0; ni < 4; ++ni)
      bias[ni] = bb[ccol0 + ni * 16] + bq[ccol0 + ni * 16];
#pragma unroll
    for (int mi = 0; mi < 8; ++mi)
#pragma unroll
      for (int rg = 0; rg < 4; ++rg) {
        int rr = crow + mi * 16 + rg;
        if (rr < cn) {
#pragma unroll
          for (int ni = 0; ni < 4; ++ni)
            oout[(size_t)(be + rr) * HID + ccol0 + ni * 16] =
                f2b(fmaxf(acc[mi][ni][rg] + bias[ni], 0.f));
        }
      }
  } else {
    const float* bb = b3 + (size_t)e * DOUTN;
    float bias[4];
#pragma unroll
    for (int ni = 0; ni < 4; ++ni) bias[ni] = bb[ccol0 + ni * 16];
#pragma unroll
    for (int mi = 0; mi < 8; ++mi)
#pragma unroll
      for (int rg = 0; rg < 4; ++rg) {
        int rr = crow + mi * 16 + rg;
        if (rr < cn) {
          float wgt = rw[be + rr];
#pragma unroll
          for (int ni = 0; ni < 4; ++ni)
            s3[(size_t)(be + rr) * DOUTN + ccol0 + ni * 16] =
                (acc[mi][ni][rg] + bias[ni]) * wgt;
        }
      }
  }
}

// ---------------- launch ----------------

extern "C" void kernel_launch(void* const* d_in, const int* in_sizes, int n_in,
                              void* d_out, int out_size, void* d_ws,
                              size_t ws_size, hipStream_t stream) {
  const float* x = (const float*)d_in[0];
  const float* w1 = (const float*)d_in[1];
  const float* b1 = (const float*)d_in[2];
  const float* w2 = (const float*)d_in[3];
  const float* b2 = (const float*)d_in[4];
  const float* w3 = (const float*)d_in[5];
  const float* b3 = (const float*)d_in[6];
  const float* wp = (const float*)d_in[7];
  const float* bp = (const float*)d_in[8];
  const float* gw1 = (const float*)d_in[9];
  const float* gb1 = (const float*)d_in[10];
  const float* gw2 = (const float*)d_in[11];
  const float* gb2 = (const float*)d_in[12];
  float* outp = (float*)d_out;
  char* ws = (char*)d_ws;

  // workspace layout (~325.4 MiB)
  const size_t o_w2p = 0;                                   // [E][2048][3072] bf16 = 100.7 MB
  const size_t o_w3t = o_w2p + (size_t)NEXP * HID * 3072 * 2;      // 33.5 MB
  const size_t o_xb  = o_w3t + (size_t)NEXP * DOUTN * HID * 2;     // 16.8 MB
  const size_t o_w1t = o_xb + (size_t)TOK * DIN * 2;               // 33.5 MB
  const size_t o_hg  = o_w1t + (size_t)NEXP * HID * DIN * 2;       // 33.5 MB
  const size_t o_hx  = o_hg + (size_t)TOK * GHID * 4;              // 100.7 MB
  const size_t o_gw1t3 = o_hx + (size_t)2 * TOK * 3072 * 2;        // 6.3 MB
  const size_t o_gidx = o_gw1t3 + (size_t)GHID * 3072 * 2;
  const size_t o_gw  = o_gidx + (size_t)2 * TOK * 4;
  const size_t o_cnt = o_gw + (size_t)2 * TOK * 4;
  const size_t o_base = o_cnt + 128;
  const size_t o_cur = o_base + 128;
  const size_t o_rt  = o_cur + 128;
  const size_t o_rw  = o_rt + (size_t)2 * TOK * 4;
  const size_t o_inv = o_rw + (size_t)2 * TOK * 4;
  // aliases (sequential-stream safe):
  const size_t o_xcat = o_hx;   // gating A (50 MB) in hx region; dead before xgather
  const size_t o_ob   = o_w1t;  // obuf bf16 [16384][2048] (67.1 MB) = w1t(33.5)+hg(33.5), both dead at MODE2
  const size_t o_s3   = o_w2p;  // s3 fp32 [16384][1024] (67.1 MB) in w2p region, dead at MODE3

  unsigned short* w2p = (unsigned short*)(ws + o_w2p);
  unsigned short* w3t = (unsigned short*)(ws + o_w3t);
  unsigned short* xb = (unsigned short*)(ws + o_xb);
  unsigned short* w1t = (unsigned short*)(ws + o_w1t);
  float* hg = (float*)(ws + o_hg);
  unsigned short* hx = (unsigned short*)(ws + o_hx);
  unsigned short* gw1t3 = (unsigned short*)(ws + o_gw1t3);
  unsigned short* xcat = (unsigned short*)(ws + o_xcat);
  unsigned short* obuf = (unsigned short*)(ws + o_ob);
  float* s3 = (float*)(ws + o_s3);
  int* gidx = (int*)(ws + o_gidx);
  float* gwt = (float*)(ws + o_gw);
  int* cnt = (int*)(ws + o_cnt);
  int* basep = (int*)(ws + o_base);
  int* cur = (int*)(ws + o_cur);
  int* rtl = (int*)(ws + o_rt);
  float* rwl = (float*)(ws + o_rw);
  int* invp = (int*)(ws + o_inv);

  hipMemsetAsync(ws + o_cnt, 0, 32, stream);

  cvt_x_kernel<<<dim3(TOK * DIN / 4 / 256), 256, 0, stream>>>(x, xb, xcat, TOK * DIN / 4);
  cvt_gw1_kernel<<<dim3(GHID / 32, DIN / 32), dim3(32, 8), 0, stream>>>(gw1, gw1t3);
  // w1 [E][1024][2048] -> w1t [E][2048][1024]
  cvt_transpose_v2<<<dim3(HID / 64, DIN / 64, NEXP), 256, 0, stream>>>(
      w1, w1t, HID, (long)DIN * HID, (long)HID * DIN, DIN);
  // w2 [E][2048][2048] -> w2p[:, :, 0:2048]
  cvt_transpose_v2<<<dim3(HID / 64, HID / 64, NEXP), 256, 0, stream>>>(
      w2, w2p, HID, (long)HID * HID, (long)HID * 3072, 3072);
  // wp [E][1024][2048] -> w2p[:, :, 2048:3072]
  cvt_transpose_v2<<<dim3(HID / 64, DIN / 64, NEXP), 256, 0, stream>>>(
      wp, w2p + 2048, HID, (long)DIN * HID, (long)HID * 3072, 3072);
  // w3 [E][2048][1024] -> w3t [E][1024][2048]
  cvt_transpose_v2<<<dim3(DOUTN / 64, HID / 64, NEXP), 256, 0, stream>>>(
      w3, w3t, DOUTN, (long)HID * DOUTN, (long)DOUTN * HID, HID);

  gating_mfma<<<dim3(GHID / 128, TOK / 128), 256, 0, stream>>>(xcat, gw1t3, gb1, hg);
  gating2_topk<<<dim3(TOK / 4), 256, 0, stream>>>(hg, gw2, gb2, gidx, gwt);
  route_count<<<dim3(TOK / 256), 256, 0, stream>>>(gidx, cnt);
  route_scan<<<1, 64, 0, stream>>>(cnt, basep, cur);
  route_scatter<<<dim3(TOK / 256), 256, 0, stream>>>(gidx, gwt, cur, rtl, rwl, invp);
  xgather_kernel<<<dim3(2 * TOK), 128, 0, stream>>>(xb, rtl, hx);

  // max row tiles: sum_e ceil(cnt_e/256) <= 16384/256 + 7 = 71
  moe_gemm8<1><<<dim3(HID / 256, 71), 512, 0, stream>>>(
      hx, obuf, w1t, w2p, w3t, b1, b2, bp, b3, rwl, cnt, basep, hx, obuf, s3);
  moe_gemm8<2><<<dim3(HID / 256, 71), 512, 0, stream>>>(
      hx, obuf, w1t, w2p, w3t, b1, b2, bp, b3, rwl, cnt, basep, hx, obuf, s3);
  moe_gemm8<3><<<dim3(DOUTN / 256, 71), 512, 0, stream>>>(
      hx, obuf, w1t, w2p, w3t, b1, b2, bp, b3, rwl, cnt, basep, hx, obuf, s3);

  combine_kernel<<<dim3(TOK), 256, 0, stream>>>(s3, invp, outp);
}

// Round 2
// 1014.605 us; speedup vs baseline: 1.1018x; 1.0179x over previous
//
#include <hip/hip_runtime.h>
#include <hip/hip_bf16.h>
#include <cstdint>
#include <cstddef>

#define TOK  8192
#define DIN  1024
#define HID  2048
#define DOUTN 1024
#define NEXP 8
#define GHID 1024

typedef __attribute__((ext_vector_type(8))) short bf16x8;
typedef __attribute__((ext_vector_type(4))) float floatx4;
typedef __attribute__((ext_vector_type(8))) unsigned short ushort8v;

__device__ __forceinline__ unsigned short f2b(float f) {
  unsigned int u = __float_as_uint(f);
  u += 0x7fffu + ((u >> 16) & 1u);
  return (unsigned short)(u >> 16);
}

__device__ __forceinline__ float b2f(unsigned short b) {
  return __uint_as_float(((unsigned int)b) << 16);
}

__device__ __forceinline__ void async_cp16(const unsigned short* g, char* lds) {
  __builtin_amdgcn_global_load_lds(
      (const __attribute__((address_space(1))) unsigned int*)g,
      (__attribute__((address_space(3))) unsigned int*)lds, 16, 0, 0);
}

// ---------------- conversions ----------------

// x fp32 -> xb (bf16 hi) and xcat [TOK][3072] = [hi | hi | lo] (gating A operand)
__global__ void cvt_x_kernel(const float* __restrict__ src,
                             unsigned short* __restrict__ xb,
                             unsigned short* __restrict__ xcat, int n4) {
  int i = blockIdx.x * blockDim.x + threadIdx.x;
  if (i >= n4) return;
  float4 v = ((const float4*)src)[i];
  ushort4 hi, lo;
  hi.x = f2b(v.x); lo.x = f2b(v.x - b2f(hi.x));
  hi.y = f2b(v.y); lo.y = f2b(v.y - b2f(hi.y));
  hi.z = f2b(v.z); lo.z = f2b(v.z - b2f(hi.z));
  hi.w = f2b(v.w); lo.w = f2b(v.w - b2f(hi.w));
  ((ushort4*)xb)[i] = hi;
  int t = i >> 8;        // DIN/4 = 256 float4 per row
  int kk = i & 255;
  ushort4* rowc = (ushort4*)(xcat + (size_t)t * 3072);
  rowc[kk] = hi;
  rowc[256 + kk] = hi;
  rowc[512 + kk] = lo;
}

// src [E][K][N] fp32 -> dst [E][N][ldDst] bf16 (64x64 tiles, vectorized)
__global__ void cvt_transpose_v2(const float* __restrict__ src,
                                 unsigned short* __restrict__ dst, int N,
                                 long sEstride, long dEstride, int ldDst) {
  __shared__ __align__(16) unsigned short t[64][72];
  long e = blockIdx.z;
  src += e * sEstride;
  dst += e * dEstride;
  int n0 = blockIdx.x * 64, k0 = blockIdx.y * 64;
  int tid = threadIdx.x;
  int kr = tid >> 2, qc = tid & 3;
  const float* s = src + (long)(k0 + kr) * N + n0 + qc * 16;
#pragma unroll
  for (int i = 0; i < 4; i++) {
    float4 v = *(const float4*)(s + i * 4);
    int nn = qc * 16 + i * 4;
    t[nn + 0][kr] = f2b(v.x);
    t[nn + 1][kr] = f2b(v.y);
    t[nn + 2][kr] = f2b(v.z);
    t[nn + 3][kr] = f2b(v.w);
  }
  __syncthreads();
  int c = tid & 7;     // 16B chunk along k
  int nr = tid >> 3;   // 0..31
#pragma unroll
  for (int p = 0; p < 2; p++) {
    int n = nr + 32 * p;
    ushort8v v = *(const ushort8v*)&t[n][c * 8];
    *(ushort8v*)(dst + (long)(n0 + n) * ldDst + k0 + c * 8) = v;
  }
}

// gw1 [DIN][GHID] fp32 -> gw1t3 [GHID][3072] bf16 = [W_hi^T | W_lo^T | W_hi^T]
__global__ void cvt_gw1_kernel(const float* __restrict__ src,
                               unsigned short* __restrict__ dst) {
  __shared__ float tile[32][33];
  int n0 = blockIdx.x * 32, k0 = blockIdx.y * 32;
  int x = threadIdx.x, y = threadIdx.y;
#pragma unroll
  for (int i = 0; i < 4; i++)
    tile[y + 8 * i][x] = src[(long)(k0 + y + 8 * i) * GHID + n0 + x];
  __syncthreads();
#pragma unroll
  for (int i = 0; i < 4; i++) {
    float v = tile[x][y + 8 * i];
    unsigned short hi = f2b(v);
    unsigned short lo = f2b(v - b2f(hi));
    size_t r = (size_t)(n0 + y + 8 * i) * 3072 + k0 + x;
    dst[r] = hi;
    dst[r + 1024] = lo;
    dst[r + 2048] = hi;
  }
}

// ---------------- gating: logits + top-2 + softmax ----------------
// H0/H1 are raw fp32 K-split partials from moe_gemm8<0>; fuse add+bias+relu.

__global__ void gating2_topk(const float* __restrict__ H0,
                             const float* __restrict__ H1,
                             const float* __restrict__ gb1,
                             const float* __restrict__ gw2,
                             const float* __restrict__ gb2,
                             int* __restrict__ gidx, float* __restrict__ gwt) {
  int wv = threadIdx.x >> 6, lane = threadIdx.x & 63;
  int t = blockIdx.x * 4 + wv;
  const float* h0 = H0 + (size_t)t * GHID;
  const float* h1 = H1 + (size_t)t * GHID;
  float acc[8] = {};
  for (int k = lane; k < GHID; k += 64) {
    float v = fmaxf(h0[k] + h1[k] + gb1[k], 0.f);
    float4 g0 = *(const float4*)(gw2 + (size_t)k * 8);
    float4 g1 = *(const float4*)(gw2 + (size_t)k * 8 + 4);
    acc[0] += v * g0.x; acc[1] += v * g0.y; acc[2] += v * g0.z; acc[3] += v * g0.w;
    acc[4] += v * g1.x; acc[5] += v * g1.y; acc[6] += v * g1.z; acc[7] += v * g1.w;
  }
#pragma unroll
  for (int off = 32; off > 0; off >>= 1)
#pragma unroll
    for (int e = 0; e < 8; e++) acc[e] += __shfl_xor(acc[e], off);

  if (lane == 0) {
    float l[8];
#pragma unroll
    for (int e = 0; e < 8; e++) l[e] = acc[e] + gb2[e];
    int b0 = 0; float v0 = l[0];
#pragma unroll
    for (int e = 1; e < 8; e++) if (l[e] > v0) { v0 = l[e]; b0 = e; }
    int b1 = -1; float v1 = -3.4e38f;
#pragma unroll
    for (int e = 0; e < 8; e++)
      if (e != b0 && l[e] > v1) { v1 = l[e]; b1 = e; }
    float ex = expf(v1 - v0);
    float inv = 1.f / (1.f + ex);
    gidx[2 * t] = b0; gidx[2 * t + 1] = b1;
    gwt[2 * t] = inv; gwt[2 * t + 1] = ex * inv;
  }
}

// ---------------- routing: count / scan / scatter ----------------

__global__ void route_count(const int* __restrict__ gidx, int* cnt) {
  int t = blockIdx.x * blockDim.x + threadIdx.x;
  int lane = threadIdx.x & 63;
  int e0 = gidx[2 * t], e1 = gidx[2 * t + 1];
#pragma unroll 1
  for (int e = 0; e < NEXP; e++) {
    unsigned long long m0 = __ballot(e0 == e);
    if (m0 && lane == __ffsll(m0) - 1) atomicAdd(&cnt[e], (int)__popcll(m0));
    unsigned long long m1 = __ballot(e1 == e);
    if (m1 && lane == __ffsll(m1) - 1) atomicAdd(&cnt[e], (int)__popcll(m1));
  }
}

__global__ void route_scan(const int* __restrict__ cnt, int* base_, int* cur) {
  if (threadIdx.x == 0) {
    int s = 0;
    for (int e = 0; e < NEXP; e++) { base_[e] = s; cur[e] = s; s += cnt[e]; }
  }
}

__global__ void route_scatter(const int* __restrict__ gidx,
                              const float* __restrict__ gwt, int* cur,
                              int* __restrict__ rt, float* __restrict__ rw,
                              int* __restrict__ inv) {
  int t = blockIdx.x * blockDim.x + threadIdx.x;
  int lane = threadIdx.x & 63;
  int e0 = gidx[2 * t], e1 = gidx[2 * t + 1];
  float w0 = gwt[2 * t], w1 = gwt[2 * t + 1];
#pragma unroll 1
  for (int e = 0; e < NEXP; e++) {
#pragma unroll 1
    for (int s = 0; s < 2; s++) {
      int mye = s ? e1 : e0;
      unsigned long long m = __ballot(mye == e);
      if (m) {
        int leader = __ffsll(m) - 1;
        int bb = 0;
        if (lane == leader) bb = atomicAdd(&cur[e], (int)__popcll(m));
        bb = __shfl(bb, leader);
        if (mye == e) {
          int pos = bb + (int)__popcll(m & ((1ull << lane) - 1ull));
          rt[pos] = t;
          rw[pos] = s ? w1 : w0;
          inv[2 * t + s] = pos;
        }
      }
    }
  }
}

// gather x rows into hx[slot][2048..3071]
__global__ void xgather_kernel(const unsigned short* __restrict__ xb,
                               const int* __restrict__ rt,
                               unsigned short* __restrict__ hx) {
  int slot = blockIdx.x;
  int c = threadIdx.x;  // 128 threads x ushort8 = 1024 elems
  int t = rt[slot];
  ((ushort8v*)(hx + (size_t)slot * 3072 + 2048))[c] =
      ((const ushort8v*)(xb + (size_t)t * 1024))[c];
}

// out[t] = sum of both K-split halves of both selected experts
__global__ void combine_kernel(const float* __restrict__ s3,
                               const float* __restrict__ s3b,
                               const int* __restrict__ inv,
                               float* __restrict__ out) {
  int t = blockIdx.x;
  int c = threadIdx.x;  // 256 threads x float4 = 1024
  int i0 = inv[2 * t], i1 = inv[2 * t + 1];
  float4 a = ((const float4*)(s3 + (size_t)i0 * DOUTN))[c];
  float4 b = ((const float4*)(s3 + (size_t)i1 * DOUTN))[c];
  float4 a2 = ((const float4*)(s3b + (size_t)i0 * DOUTN))[c];
  float4 b2 = ((const float4*)(s3b + (size_t)i1 * DOUTN))[c];
  float4 o = {a.x + b.x + a2.x + b2.x, a.y + b.y + a2.y + b2.y,
              a.z + b.z + a2.z + b2.z, a.w + b.w + a2.w + b2.w};
  ((float4*)(out + (size_t)t * DOUTN))[c] = o;
}

// ---------------- GEMMs: 256x256xBK64, 8-phase counted-vmcnt ----------------
// m201 8-phase template. 512 threads = 8 waves (2M x 4N); per-wave C 128x64.
// LDS 128 KiB double-buffered; chunk-swizzled rows (rule #21: pre-swizzled
// global source + linear global_load_lds dest; read slot ((kk<<2)|q)^(l15&7)).
// Stage schedule/vmcnt ledger verified in round-0 (A h0 = units {0,2},
// h1 = {1,3}; B c0/c1 = first/second 32 rows of every unit).
//
// Tile->XCD mapping: bijective 8-way chunk (m204) + COLUMN-MAJOR tile order
// (by = wg % gy). For nwg = 8*71 each XCD owns exactly one N-column: its B
// working set is 1-2 expert panels (<=3 MB) at a time -> L2-resident B
// refetch, L3 only streams A. (Row-major chunks spanned ~9 A + 8 B panels
// = 26 MB, thrashing the 4 MiB XCD L2 -> everything streamed from L3.)
//
// MODE 0: hg[kz]        = xcat @ gw1t3 (raw fp32 partial)   K=1536 (kz half)
// MODE 1: hx[:,0:2048]  = relu(hx[:,2048:] @ w1 + b1)       K=1024
// MODE 2: obuf          = relu(hx @ [w2;wp] + b2 + bp)      K=3072
// MODE 3: s3/s3b        = (obuf @ w3 [+ b3]) * gatew        K=1024 (kz half)

#define STG_AU(dst, u, ktI)                                                   \
  async_cp16(Abase + aOff[u] + (size_t)(ktI) * 64, (dst) + (u) * 8192 + wvb)
#define STG_BU(dst, u, ktI)                                                   \
  async_cp16(Bbase + bOff[u] + (size_t)(ktI) * 64, (dst) + (u) * 8192 + wvb)

#define LDA8(dst, baseA, h)                                                   \
  _Pragma("unroll") for (int mi = 0; mi < 4; ++mi)                            \
      _Pragma("unroll") for (int kk = 0; kk < 2; ++kk)                        \
          (dst)[mi * 2 + kk] = *(const bf16x8*)(                              \
              (baseA) + ((wmo + (h)*64 + mi * 16 + l15) * 128 +               \
                         ((s0 ^ (kk << 2)) * 16)));

#define LDB4(dst, baseB, ch)                                                  \
  _Pragma("unroll") for (int ni = 0; ni < 2; ++ni)                            \
      _Pragma("unroll") for (int kk = 0; kk < 2; ++kk)                        \
          (dst)[ni * 2 + kk] = *(const bf16x8*)(                              \
              (baseB) + ((wno + (ch)*32 + ni * 16 + l15) * 128 +              \
                         ((s0 ^ (kk << 2)) * 16)));

#define MM8(aF, bF, mo, no)                                                   \
  _Pragma("unroll") for (int mi = 0; mi < 4; ++mi)                            \
      _Pragma("unroll") for (int ni = 0; ni < 2; ++ni)                        \
          _Pragma("unroll") for (int kk = 0; kk < 2; ++kk)                    \
              acc[(mo) + mi][(no) + ni] =                                     \
                  __builtin_amdgcn_mfma_f32_16x16x32_bf16(                    \
                      (aF)[mi * 2 + kk], (bF)[ni * 2 + kk],                   \
                      acc[(mo) + mi][(no) + ni], 0, 0, 0);

template <int MODE>
__global__ __launch_bounds__(512, 2) void moe_gemm8(
    const unsigned short* __restrict__ hx, const unsigned short* __restrict__ obuf,
    const unsigned short* __restrict__ w1t, const unsigned short* __restrict__ w2p,
    const unsigned short* __restrict__ w3t, const unsigned short* __restrict__ xcat,
    const unsigned short* __restrict__ gw1t3, const float* __restrict__ b1,
    const float* __restrict__ b2, const float* __restrict__ bp,
    const float* __restrict__ b3, const float* __restrict__ rw,
    const int* __restrict__ cnt, const int* __restrict__ basep,
    unsigned short* __restrict__ hxout, unsigned short* __restrict__ oout,
    float* __restrict__ s3, float* __restrict__ s3b,
    float* __restrict__ hg0, float* __restrict__ hg1) {
  __shared__ __align__(16) char smem[131072];

  // bijective XCD chunking + column-major tile order
  const int gx = (int)gridDim.x, gy = (int)gridDim.y;
  const int kz = (int)blockIdx.z;
  const int nwg = gx * gy;
  int orig = (int)blockIdx.y * gx + (int)blockIdx.x;
  int q8 = nwg >> 3, r8 = nwg & 7;
  int xcd = orig & 7, loc = orig >> 3;
  int wg = (xcd < r8 ? xcd * (q8 + 1) : r8 * (q8 + 1) + (xcd - r8) * q8) + loc;
  int by = wg % gy, bx = wg / gy;

  // expert / row-tile lookup
  int e = 0, cn = TOK, be = 0, row0 = by << 8;
  if (MODE != 0) {
    int lt = by, ok = 0;
    cn = 0;
    for (e = 0; e < NEXP; ++e) {
      int c = cnt[e];
      int nt = (c + 255) >> 8;
      if (lt < nt) { cn = c; ok = 1; break; }
      lt -= nt;
    }
    if (!ok) return;
    be = basep[e];
    row0 = lt << 8;
  }
  const int tn = bx << 8;
  const int cnm1 = cn - 1;

  const int tid = threadIdx.x;
  const int lane = tid & 63, wv = tid >> 6;
  const int wmo = (wv >> 2) * 128;  // wave M offset: 0 / 128
  const int wno = (wv & 3) * 64;    // wave N offset: 0 / 64 / 128 / 192
  const int q = lane >> 4, l15 = lane & 15;
  const int s0 = q ^ (l15 & 7);     // read-side swizzle slot (kk=0)
  const int wvb = wv * 1024;
  const int srow = tid >> 3;                       // 0..63
  const int skoff = ((tid & 7) ^ (srow & 7)) * 8;  // pre-swizzled src k chunk

  const unsigned short* Abase;
  const unsigned short* Bbase;
  size_t strideA, strideB;
  int NT;
  if (MODE == 0) {
    Abase = xcat + (size_t)kz * 1536; strideA = 3072;
    Bbase = gw1t3 + (size_t)kz * 1536; strideB = 3072;
    NT = 1536 / 64;
  } else if (MODE == 1) {
    Abase = hx + 2048; strideA = 3072;
    Bbase = w1t + (size_t)e * HID * DIN; strideB = DIN;
    NT = DIN / 64;
  } else if (MODE == 2) {
    Abase = hx; strideA = 3072;
    Bbase = w2p + (size_t)e * HID * 3072; strideB = 3072;
    NT = 3072 / 64;
  } else {
    Abase = obuf + (size_t)kz * 1024; strideA = HID;
    Bbase = w3t + (size_t)e * DOUTN * HID + (size_t)kz * 1024; strideB = HID;
    NT = 1024 / 64;
  }

  // per-thread staging source offsets (elements), rows clamped per thread
  size_t aOff[4], bOff[4];
#pragma unroll
  for (int u = 0; u < 4; ++u) {
    int ra = min(row0 + u * 64 + srow, cnm1);
    aOff[u] = (size_t)(be + ra) * strideA + skoff;
    bOff[u] = (size_t)(tn + u * 64 + srow) * strideB + skoff;
  }

  char* const A0s = smem;           // buf0 A [256][64] bf16
  char* const B0s = smem + 32768;   // buf0 B
  char* const A1s = smem + 65536;   // buf1 A
  char* const B1s = smem + 98304;   // buf1 B

  floatx4 acc[8][4] = {};
  bf16x8 a[8], bA[4], bB[4];

  // ---- prologue: tile0 fully, then 6/8 units of tile1 ----
  STG_AU(A0s, 0, 0); STG_AU(A0s, 1, 0); STG_AU(A0s, 2, 0); STG_AU(A0s, 3, 0);
  STG_BU(B0s, 0, 0); STG_BU(B0s, 1, 0); STG_BU(B0s, 2, 0); STG_BU(B0s, 3, 0);
  asm volatile("s_waitcnt vmcnt(4)" ::: "memory");
  STG_AU(A1s, 0, 1); STG_AU(A1s, 2, 1);
  STG_BU(B1s, 0, 1); STG_BU(B1s, 1, 1);
  STG_AU(A1s, 1, 1); STG_AU(A1s, 3, 1);
  asm volatile("s_waitcnt vmcnt(6)" ::: "memory");
  __builtin_amdgcn_s_barrier();

  for (int t = 0; t < NT; ++t) {
    char* const curA = (t & 1) ? A1s : A0s;
    char* const curB = (t & 1) ? B1s : B0s;
    char* const nxtB = (t & 1) ? B0s : B1s;
    // ---- P0 ----
    LDA8(a, curA, 0);
    LDB4(bA, curB, 0);
    if (t + 1 < NT) { STG_BU(nxtB, 2, t + 1); STG_BU(nxtB, 3, t + 1); }
    __builtin_amdgcn_s_barrier();
    asm volatile("s_waitcnt lgkmcnt(0)" ::: "memory");
    __builtin_amdgcn_s_setprio(1);
    MM8(a, bA, 0, 0);
    __builtin_amdgcn_s_setprio(0);
    __builtin_amdgcn_s_barrier();
    // ---- P1 ----
    LDB4(bB, curB, 1);
    if (t + 2 < NT) { STG_AU(curA, 0, t + 2); STG_AU(curA, 2, t + 2); }
    __builtin_amdgcn_s_barrier();
    asm volatile("s_waitcnt lgkmcnt(0)" ::: "memory");
    __builtin_amdgcn_s_setprio(1);
    MM8(a, bB, 0, 2);
    __builtin_amdgcn_s_setprio(0);
    __builtin_amdgcn_s_barrier();
    // ---- P2 ----
    LDA8(a, curA, 1);
    if (t + 2 < NT) { STG_BU(curB, 0, t + 2); STG_BU(curB, 1, t + 2); }
    __builtin_amdgcn_s_barrier();
    asm volatile("s_waitcnt lgkmcnt(0)" ::: "memory");
    __builtin_amdgcn_s_setprio(1);
    MM8(a, bB, 4, 2);
    __builtin_amdgcn_s_setprio(0);
    __builtin_amdgcn_s_barrier();
    // ---- P3 (regs only; counted vmcnt, never 0 mid-loop) ----
    if (t + 2 < NT) {
      STG_AU(curA, 1, t + 2); STG_AU(curA, 3, t + 2);
      __builtin_amdgcn_s_setprio(1);
      MM8(a, bA, 4, 0);
      __builtin_amdgcn_s_setprio(0);
      asm volatile("s_waitcnt vmcnt(6)" ::: "memory");
    } else {
      __builtin_amdgcn_s_setprio(1);
      MM8(a, bA, 4, 0);
      __builtin_amdgcn_s_setprio(0);
      asm volatile("s_waitcnt vmcnt(0)" ::: "memory");
    }
    __builtin_amdgcn_s_barrier();
  }

  // ---- epilogue (C/D: col=lane&15, row=(lane>>4)*4+reg; frag offsets 16*idx)
  const int crow = row0 + wmo + q * 4;
  const int ccol0 = tn + wno + l15;
  if (MODE == 0) {
    float* Hp = kz ? hg1 : hg0;
#pragma unroll
    for (int mi = 0; mi < 8; ++mi)
#pragma unroll
      for (int rg = 0; rg < 4; ++rg) {
        int rr = crow + mi * 16 + rg;
#pragma unroll
        for (int ni = 0; ni < 4; ++ni)
          Hp[(size_t)rr * GHID + ccol0 + ni * 16] = acc[mi][ni][rg];
      }
  } else if (MODE == 1) {
    const float* bb = b1 + (size_t)e * HID;
    float bias[4];
#pragma unroll
    for (int ni = 0; ni < 4; ++ni) bias[ni] = bb[ccol0 + ni * 16];
#pragma unroll
    for (int mi = 0; mi < 8; ++mi)
#pragma unroll
      for (int rg = 0; rg < 4; ++rg) {
        int rr = crow + mi * 16 + rg;
        if (rr < cn) {
#pragma unroll
          for (int ni = 0; ni < 4; ++ni)
            hxout[(size_t)(be + rr) * 3072 + ccol0 + ni * 16] =
                f2b(fmaxf(acc[mi][ni][rg] + bias[ni], 0.f));
        }
      }
  } else if (MODE == 2) {
    const float* bb = b2 + (size_t)e * HID;
    const float* bq = bp + (size_t)e * HID;
    float bias[4];
#pragma unroll
    for (int ni = 0; ni < 4; ++ni)
      bias[ni] = bb[ccol0 + ni * 16] + bq[ccol0 + ni * 16];
#pragma unroll
    for (int mi = 0; mi < 8; ++mi)
#pragma unroll
      for (int rg = 0; rg < 4; ++rg) {
        int rr = crow + mi * 16 + rg;
        if (rr < cn) {
#pragma unroll
          for (int ni = 0; ni < 4; ++ni)
            oout[(size_t)(be + rr) * HID + ccol0 + ni * 16] =
                f2b(fmaxf(acc[mi][ni][rg] + bias[ni], 0.f));
        }
      }
  } else {
    const float* bb = b3 + (size_t)e * DOUTN;
    float* dst = kz ? s3b : s3;
    float bias[4];
#pragma unroll
    for (int ni = 0; ni < 4; ++ni)
      bias[ni] = kz ? 0.f : bb[ccol0 + ni * 16];  // b3 applied once (kz==0)
#pragma unroll
    for (int mi = 0; mi < 8; ++mi)
#pragma unroll
      for (int rg = 0; rg < 4; ++rg) {
        int rr = crow + mi * 16 + rg;
        if (rr < cn) {
          float wgt = rw[be + rr];
#pragma unroll
          for (int ni = 0; ni < 4; ++ni)
            dst[(size_t)(be + rr) * DOUTN + ccol0 + ni * 16] =
                (acc[mi][ni][rg] + bias[ni]) * wgt;
        }
      }
  }
}

// ---------------- launch ----------------

extern "C" void kernel_launch(void* const* d_in, const int* in_sizes, int n_in,
                              void* d_out, int out_size, void* d_ws,
                              size_t ws_size, hipStream_t stream) {
  const float* x = (const float*)d_in[0];
  const float* w1 = (const float*)d_in[1];
  const float* b1 = (const float*)d_in[2];
  const float* w2 = (const float*)d_in[3];
  const float* b2 = (const float*)d_in[4];
  const float* w3 = (const float*)d_in[5];
  const float* b3 = (const float*)d_in[6];
  const float* wp = (const float*)d_in[7];
  const float* bp = (const float*)d_in[8];
  const float* gw1 = (const float*)d_in[9];
  const float* gb1 = (const float*)d_in[10];
  const float* gw2 = (const float*)d_in[11];
  const float* gb2 = (const float*)d_in[12];
  float* outp = (float*)d_out;
  char* ws = (char*)d_ws;

  // workspace layout (~325.4 MiB)
  const size_t o_w2p = 0;                                   // [E][2048][3072] bf16 = 100.7 MB
  const size_t o_w3t = o_w2p + (size_t)NEXP * HID * 3072 * 2;      // 33.5 MB
  const size_t o_xb  = o_w3t + (size_t)NEXP * DOUTN * HID * 2;     // 16.8 MB
  const size_t o_w1t = o_xb + (size_t)TOK * DIN * 2;               // 33.5 MB
  const size_t o_hg  = o_w1t + (size_t)NEXP * HID * DIN * 2;       // 33.5 MB
  const size_t o_hx  = o_hg + (size_t)TOK * GHID * 4;              // 100.7 MB
  const size_t o_gw1t3 = o_hx + (size_t)2 * TOK * 3072 * 2;        // 6.3 MB
  const size_t o_gidx = o_gw1t3 + (size_t)GHID * 3072 * 2;
  const size_t o_gw  = o_gidx + (size_t)2 * TOK * 4;
  const size_t o_cnt = o_gw + (size_t)2 * TOK * 4;
  const size_t o_base = o_cnt + 128;
  const size_t o_cur = o_base + 128;
  const size_t o_rt  = o_cur + 128;
  const size_t o_rw  = o_rt + (size_t)2 * TOK * 4;
  const size_t o_inv = o_rw + (size_t)2 * TOK * 4;
  // aliases (sequential-stream safe):
  const size_t o_xcat = o_hx;                    // gating A (50.3 MB); dead before xgather
  const size_t o_hg2  = o_hx + (size_t)TOK * 3072 * 2;  // K-split partial 2 (33.5 MB); dead before xgather
  const size_t o_ob   = o_w1t;  // obuf bf16 [16384][2048] (67.1 MB) = w1t+hg, both dead at MODE2
  const size_t o_s3   = o_w2p;  // s3 fp32 [16384][1024] (67.1 MB) in w2p region, dead at MODE3
  const size_t o_s3b  = o_hx;   // s3b fp32 (67.1 MB) in hx region, hx dead after MODE2

  unsigned short* w2p = (unsigned short*)(ws + o_w2p);
  unsigned short* w3t = (unsigned short*)(ws + o_w3t);
  unsigned short* xb = (unsigned short*)(ws + o_xb);
  unsigned short* w1t = (unsigned short*)(ws + o_w1t);
  float* hg = (float*)(ws + o_hg);
  float* hg2 = (float*)(ws + o_hg2);
  unsigned short* hx = (unsigned short*)(ws + o_hx);
  unsigned short* gw1t3 = (unsigned short*)(ws + o_gw1t3);
  unsigned short* xcat = (unsigned short*)(ws + o_xcat);
  unsigned short* obuf = (unsigned short*)(ws + o_ob);
  float* s3 = (float*)(ws + o_s3);
  float* s3b = (float*)(ws + o_s3b);
  int* gidx = (int*)(ws + o_gidx);
  float* gwt = (float*)(ws + o_gw);
  int* cnt = (int*)(ws + o_cnt);
  int* basep = (int*)(ws + o_base);
  int* cur = (int*)(ws + o_cur);
  int* rtl = (int*)(ws + o_rt);
  float* rwl = (float*)(ws + o_rw);
  int* invp = (int*)(ws + o_inv);

  hipMemsetAsync(ws + o_cnt, 0, 32, stream);

  cvt_x_kernel<<<dim3(TOK * DIN / 4 / 256), 256, 0, stream>>>(x, xb, xcat, TOK * DIN / 4);
  cvt_gw1_kernel<<<dim3(GHID / 32, DIN / 32), dim3(32, 8), 0, stream>>>(gw1, gw1t3);
  // w1 [E][1024][2048] -> w1t [E][2048][1024]
  cvt_transpose_v2<<<dim3(HID / 64, DIN / 64, NEXP), 256, 0, stream>>>(
      w1, w1t, HID, (long)DIN * HID, (long)HID * DIN, DIN);
  // w2 [E][2048][2048] -> w2p[:, :, 0:2048]
  cvt_transpose_v2<<<dim3(HID / 64, HID / 64, NEXP), 256, 0, stream>>>(
      w2, w2p, HID, (long)HID * HID, (long)HID * 3072, 3072);
  // wp [E][1024][2048] -> w2p[:, :, 2048:3072]
  cvt_transpose_v2<<<dim3(HID / 64, DIN / 64, NEXP), 256, 0, stream>>>(
      wp, w2p + 2048, HID, (long)DIN * HID, (long)HID * 3072, 3072);
  // w3 [E][2048][1024] -> w3t [E][1024][2048]
  cvt_transpose_v2<<<dim3(DOUTN / 64, HID / 64, NEXP), 256, 0, stream>>>(
      w3, w3t, DOUTN, (long)HID * DOUTN, (long)DOUTN * HID, HID);

  // gating GEMM: 4x32x2 = 256 blocks = exactly one scheduling round
  moe_gemm8<0><<<dim3(GHID / 256, TOK / 256, 2), 512, 0, stream>>>(
      hx, obuf, w1t, w2p, w3t, xcat, gw1t3, b1, b2, bp, b3, rwl, cnt, basep,
      hx, obuf, s3, s3b, hg, hg2);
  gating2_topk<<<dim3(TOK / 4), 256, 0, stream>>>(hg, hg2, gb1, gw2, gb2, gidx, gwt);
  route_count<<<dim3(TOK / 256), 256, 0, stream>>>(gidx, cnt);
  route_scan<<<1, 64, 0, stream>>>(cnt, basep, cur);
  route_scatter<<<dim3(TOK / 256), 256, 0, stream>>>(gidx, gwt, cur, rtl, rwl, invp);
  xgather_kernel<<<dim3(2 * TOK), 128, 0, stream>>>(xb, rtl, hx);

  // max row tiles: sum_e ceil(cnt_e/256) <= 16384/256 + 7 = 71
  moe_gemm8<1><<<dim3(HID / 256, 71), 512, 0, stream>>>(
      hx, obuf, w1t, w2p, w3t, xcat, gw1t3, b1, b2, bp, b3, rwl, cnt, basep,
      hx, obuf, s3, s3b, hg, hg2);
  moe_gemm8<2><<<dim3(HID / 256, 71), 512, 0, stream>>>(
      hx, obuf, w1t, w2p, w3t, xcat, gw1t3, b1, b2, bp, b3, rwl, cnt, basep,
      hx, obuf, s3, s3b, hg, hg2);
  // MODE3 K-split: 4x71x2 = 568 small blocks (kills the 284-block 1.11-round tail)
  moe_gemm8<3><<<dim3(DOUTN / 256, 71, 2), 512, 0, stream>>>(
      hx, obuf, w1t, w2p, w3t, xcat, gw1t3, b1, b2, bp, b3, rwl, cnt, basep,
      hx, obuf, s3, s3b, hg, hg2);

  combine_kernel<<<dim3(TOK), 256, 0, stream>>>(s3, s3b, invp, outp);
}